// Round 5
// baseline (396.766 us; speedup 1.0000x reference)
//
#include <hip/hip_runtime.h>
#include <hip/hip_bf16.h>

// B=16, S=2048, D=64 attention w/ symmetric pad mask.
// out = [context (B*S*D fp32), attn (B*S*S fp32)] concatenated.
//
// R5: single-pass deferred normalization. R4 ran QK^T+exp twice (pass A for
// row sums). Now: one pass accumulates unnormalized PV (linear in P) and
// stashes unnormalized bf16 P into the attn buffer itself — stash row r
// lives in the 2nd half of fp32 row r's own region (win + r*S + S/2), so
// the final expand (read bf16 row r -> scale by 1/l -> write fp32 row r)
// clobbers only the row it just read. Register dep + per-row compiler
// memory barrier order read-before-write; cross-row regions are disjoint.
#define NBATCH 16
#define SLEN   2048
#define DIM    64
#define TQ     64
#define NTHR   256
#define NW     4
#define PANEL  128
#define NPANEL (SLEN / PANEL)   // 16
#define PROWK  72               // shorts: 64 data + 8 pad
#define PROWV  136              // shorts: 128 data + 8 pad
#define PROWP  136              // shorts: 128 data + 8 pad

typedef __attribute__((ext_vector_type(8))) short bf16x8;
typedef __attribute__((ext_vector_type(4))) float f32x4;

__device__ inline short f2bf(float f) {
    union { __hip_bfloat16 h; short s; } u;
    u.h = __float2bfloat16(f);
    return u.s;
}
__device__ inline float bf2f(unsigned short s) {
    union { unsigned u; float f; } x;
    x.u = ((unsigned)s) << 16;
    return x.f;
}
__device__ inline bf16x8 pack8(float4 a, float4 b) {
    bf16x8 r;
    r[0] = f2bf(a.x); r[1] = f2bf(a.y); r[2] = f2bf(a.z); r[3] = f2bf(a.w);
    r[4] = f2bf(b.x); r[5] = f2bf(b.y); r[6] = f2bf(b.z); r[7] = f2bf(b.w);
    return r;
}

__global__ __launch_bounds__(NTHR, 3) void sdpa_kernel(
    const float* __restrict__ Q, const float* __restrict__ K,
    const float* __restrict__ V, const int* __restrict__ M,
    float* __restrict__ outCtx, float* __restrict__ outAttn)
{
    __shared__ __align__(16) short sK[128 * PROWK];     // 18.0 KB K panel bf16
    __shared__ __align__(16) short sVT[64 * PROWV];     // 17.0 KB V^T bf16 (swizzled)
    __shared__ __align__(16) short sP[NW * 16 * PROWP]; // 17.0 KB per-wave P bf16
    __shared__ float sMask[PANEL];                      // 0/1 column mask
    __shared__ float sScale[NW * 16];                   // per-row 1/l

    const int tid = threadIdx.x;
    const int w = tid >> 6, l = tid & 63, g = l >> 4, c = l & 15;
    const int b  = blockIdx.x >> 5;          // 32 blocks/batch
    const int i0 = (blockIdx.x & 31) * TQ;
    const int i0w = i0 + w * 16;             // this wave's q-row base

    const float* Kb = K + (size_t)b * SLEN * DIM;
    const float* Vb = V + (size_t)b * SLEN * DIM;
    const int*   Mb = M + b * SLEN;
    float* win = outAttn + ((size_t)b * SLEN + i0w) * SLEN;  // wave's 16-row window

    // Q A-frags: lane (g,c) holds Q[i0w + c][g*8 .. +7] (and +32)
    bf16x8 qa0, qa1;
    {
        const float* qp = Q + ((size_t)b * SLEN + i0w + c) * DIM + g * 8;
        qa0 = pack8(*(const float4*)(qp),      *(const float4*)(qp + 4));
        qa1 = pack8(*(const float4*)(qp + 32), *(const float4*)(qp + 36));
    }

    const float scl = 0.125f;   // 1/sqrt(64)
    float rsum[4] = {0.f, 0.f, 0.f, 0.f};
    f32x4 pv[4];
    #pragma unroll
    for (int nt = 0; nt < 4; nt++) pv[nt] = (f32x4){0.f, 0.f, 0.f, 0.f};
    short* sPw = sP + w * 16 * PROWP;

    // ---- Single pass: QK^T -> exp -> {rsum, PV(unnorm), bf16 stash} ----
    for (int p = 0; p < NPANEL; p++) {
        const int j0 = p * PANEL;
        #pragma unroll
        for (int it = 0; it < 8; it++) {           // stage K panel 128x64 -> bf16
            const int idx = it * NTHR + tid;
            const int row = idx >> 4, c4 = idx & 15;
            float4 kv = *(const float4*)(Kb + (size_t)(j0 + row) * DIM + c4 * 4);
            *(short4*)(sK + row * PROWK + c4 * 4) =
                make_short4(f2bf(kv.x), f2bf(kv.y), f2bf(kv.z), f2bf(kv.w));
        }
        #pragma unroll
        for (int it = 0; it < 2; it++) {           // stage V^T (4k x 4d reg transpose)
            const int task = it * NTHR + tid;
            const int k4 = task >> 4, d4g = task & 15;
            const int kb = k4 * 4, d4 = d4g * 4;
            const int colb = kb ^ ((d4g & 3) << 3);   // XOR swizzle (bank spread)
            const float* vp = Vb + (size_t)(j0 + kb) * DIM + d4;
            float4 r0 = *(const float4*)(vp);
            float4 r1 = *(const float4*)(vp + DIM);
            float4 r2 = *(const float4*)(vp + 2 * DIM);
            float4 r3 = *(const float4*)(vp + 3 * DIM);
            *(short4*)(sVT + (d4 + 0) * PROWV + colb) =
                make_short4(f2bf(r0.x), f2bf(r1.x), f2bf(r2.x), f2bf(r3.x));
            *(short4*)(sVT + (d4 + 1) * PROWV + colb) =
                make_short4(f2bf(r0.y), f2bf(r1.y), f2bf(r2.y), f2bf(r3.y));
            *(short4*)(sVT + (d4 + 2) * PROWV + colb) =
                make_short4(f2bf(r0.z), f2bf(r1.z), f2bf(r2.z), f2bf(r3.z));
            *(short4*)(sVT + (d4 + 3) * PROWV + colb) =
                make_short4(f2bf(r0.w), f2bf(r1.w), f2bf(r2.w), f2bf(r3.w));
        }
        if (tid < PANEL) sMask[tid] = Mb[j0 + tid] ? 0.f : 1.f;
        __syncthreads();

        // QK^T tiles -> exp -> per-wave bf16 panel (UNNORMALIZED) + rsum
        #pragma unroll
        for (int jt = 0; jt < 8; jt++) {
            const short* kr = sK + (jt * 16 + c) * PROWK + g * 8;
            bf16x8 kb0 = *(const bf16x8*)(kr);
            bf16x8 kb1 = *(const bf16x8*)(kr + 32);
            f32x4 acc = {0.f, 0.f, 0.f, 0.f};
            acc = __builtin_amdgcn_mfma_f32_16x16x32_bf16(qa0, kb0, acc, 0, 0, 0);
            acc = __builtin_amdgcn_mfma_f32_16x16x32_bf16(qa1, kb1, acc, 0, 0, 0);
            const float em = sMask[jt * 16 + c];
            #pragma unroll
            for (int r = 0; r < 4; r++) {
                const float e = __expf(acc[r] * scl) * em;
                rsum[r] += e;
                sPw[(g * 4 + r) * PROWP + jt * 16 + c] = f2bf(e);
            }
        }

        // PV (unnormalized): A from own P panel, B from V^T, all b128 reads
        #pragma unroll
        for (int ks = 0; ks < 4; ks++) {
            bf16x8 af = *(const bf16x8*)(sPw + c * PROWP + ks * 32 + g * 8);
            #pragma unroll
            for (int nt = 0; nt < 4; nt++) {
                const int d = nt * 16 + c;
                const int gp = g ^ ((d >> 2) & 3);
                bf16x8 bfrag = *(const bf16x8*)(sVT + d * PROWV + ks * 32 + gp * 8);
                pv[nt] = __builtin_amdgcn_mfma_f32_16x16x32_bf16(af, bfrag, pv[nt], 0, 0, 0);
            }
        }

        // bf16 stash write: stash row r sits at win + r*SLEN + SLEN/2 (floats)
        #pragma unroll
        for (int it = 0; it < 8; it++) {
            const int task = it * 64 + l;
            const int row = task >> 5, c4 = task & 31;
            short* dst = (short*)(win + (size_t)row * SLEN + SLEN / 2) + j0 + c4 * 4;
            *(ushort4*)dst =
                *(const ushort4*)((const unsigned short*)sPw + row * PROWP + c4 * 4);
        }
        __syncthreads();   // protect sK/sVT/sMask/sP before next panel
    }

    // ---- finalize: row sums -> 1/l ----
    #pragma unroll
    for (int off = 1; off < 16; off <<= 1) {
        #pragma unroll
        for (int r = 0; r < 4; r++)
            rsum[r] += __shfl_xor(rsum[r], off, 64);
    }
    float scv[4];
    #pragma unroll
    for (int r = 0; r < 4; r++) {
        const int rm = Mb[i0w + g * 4 + r];
        scv[r] = (rm || rsum[r] <= 0.f) ? 0.f : 1.f / rsum[r];
    }
    if (c == 0) {
        #pragma unroll
        for (int r = 0; r < 4; r++) sScale[w * 16 + g * 4 + r] = scv[r];
    }

    // ctx write: scale deferred-normalized PV
    #pragma unroll
    for (int nt = 0; nt < 4; nt++) {
        #pragma unroll
        for (int r = 0; r < 4; r++)
            outCtx[((size_t)b * SLEN + i0w + g * 4 + r) * DIM + nt * 16 + c] =
                pv[nt][r] * scv[r];
    }

    // ---- expand: per wave, row-by-row bf16 stash -> normalized fp32 ----
    // (last __syncthreads drained vmcnt, so stash is globally visible; each
    //  fp32 row write clobbers only its OWN row's stash, which is already in
    //  registers — ordered by data dep + the compiler memory barrier.)
    for (int row = 0; row < 16; row++) {
        const unsigned short* srow =
            (const unsigned short*)(win + (size_t)row * SLEN + SLEN / 2);
        const float sc = sScale[w * 16 + row];
        ushort4 d[8];
        #pragma unroll
        for (int it = 0; it < 8; it++)
            d[it] = *(const ushort4*)(srow + it * 256 + l * 4);
        asm volatile("" ::: "memory");   // no fp32 store before bf16 reads
        #pragma unroll
        for (int it = 0; it < 8; it++) {
            float4 o = {bf2f(d[it].x) * sc, bf2f(d[it].y) * sc,
                        bf2f(d[it].z) * sc, bf2f(d[it].w) * sc};
            *(float4*)(win + (size_t)row * SLEN + it * 256 + l * 4) = o;
        }
    }
}

extern "C" void kernel_launch(void* const* d_in, const int* in_sizes, int n_in,
                              void* d_out, int out_size, void* d_ws, size_t ws_size,
                              hipStream_t stream) {
    const float* Q = (const float*)d_in[0];
    const float* K = (const float*)d_in[1];
    const float* V = (const float*)d_in[2];
    const int*   M = (const int*)d_in[3];
    float* outCtx  = (float*)d_out;
    float* outAttn = (float*)d_out + (size_t)NBATCH * SLEN * DIM;
    dim3 grid(NBATCH * (SLEN / TQ));   // 512 blocks
    sdpa_kernel<<<grid, NTHR, 0, stream>>>(Q, K, V, M, outCtx, outAttn);
}